// Round 5
// baseline (132.992 us; speedup 1.0000x reference)
//
#include <hip/hip_runtime.h>

// ============================================================================
// R5: fix R4's measured latency-boundness (MfmaUtil 6.3%, VALUBusy 7.2%,
// occupancy 34% -> nothing busy):
//   1. B register prefetch depth 1 -> 3 steps (bf[4][2]); per-step vmcnt
//      stall on L2 (~200-400cy) now covered by ~3 steps x 4 waves/SIMD.
//   2. A tile XOR-swizzle (chunk c of row r at phys c^(r&7), no padding):
//      read conflicts 8-way -> 2-way (free); SQ_LDS_BANK_CONFLICT 1.18M -> low.
//   3. GEMM2 proto loads hoisted above the Z phase (latency under epilogue).
// ============================================================================

#define D_IN   1024
#define D_PROJ 256
#define N_C    64
#define N_ROWS 16384
#define BM     32
#define ATS 2048            // shorts per A k-tile: 32 rows x 64, no pad (4 KB)
#define Z_STRIDE 264        // D_PROJ + 8 pad

typedef float v4f __attribute__((ext_vector_type(4)));
typedef short v8s __attribute__((ext_vector_type(8)));

__device__ inline unsigned short f2bf(float f) {
  unsigned int u = __float_as_uint(f);
  u = u + 0x7fffu + ((u >> 16) & 1u);   // round-to-nearest-even
  return (unsigned short)(u >> 16);
}

// lgkm-only barrier: orders A ds_write/ds_read WITHOUT draining vmcnt,
// so in-flight X (HBM/L3) and B (L2) loads survive the barrier.
#define GBAR() do {                                              \
  asm volatile("s_waitcnt lgkmcnt(0)" ::: "memory");             \
  __builtin_amdgcn_s_barrier();                                  \
  __builtin_amdgcn_sched_barrier(0);                             \
} while (0)

// ---------------------------------------------------------------------------
// Prep (unchanged): projT bf16 [256][1024], protoB bf16 [64][256], pnorm2[64],
// mu_p[256] = mean @ proj
// ---------------------------------------------------------------------------
__global__ __launch_bounds__(256) void prep_kernel(
    const float* __restrict__ proj,      // [1024][256]
    const float* __restrict__ protos,    // [64][256]
    const float* __restrict__ mean,      // [1024]
    unsigned short* __restrict__ projT,  // [256][1024]
    unsigned short* __restrict__ protoB, // [64][256]
    float* __restrict__ pnorm2,          // [64]
    float* __restrict__ mu_p)            // [256]
{
  __shared__ float tile[64][65];
  __shared__ float part[16][17];
  const int b = blockIdx.x;
  const int t = threadIdx.x;
  if (b < 64) {
    const int k0 = (b & 15) * 64, n0 = (b >> 4) * 64;
    const int r = t >> 4, c4 = (t & 15) * 4;
    for (int rr = r; rr < 64; rr += 16) {
      const float4 v = *(const float4*)(proj + (k0 + rr) * D_PROJ + n0 + c4);
      tile[rr][c4 + 0] = v.x; tile[rr][c4 + 1] = v.y;
      tile[rr][c4 + 2] = v.z; tile[rr][c4 + 3] = v.w;
    }
    __syncthreads();
    const int n = t >> 2, kc = (t & 3) * 16;
    unsigned short o[16];
#pragma unroll
    for (int i = 0; i < 16; ++i) o[i] = f2bf(tile[kc + i][n]);
    unsigned short* dst = projT + (n0 + n) * D_IN + k0 + kc;
#pragma unroll
    for (int i = 0; i < 4; ++i) {
      ushort4 s4 = { o[4*i+0], o[4*i+1], o[4*i+2], o[4*i+3] };
      *(ushort4*)(dst + 4*i) = s4;
    }
  } else if (b < 80) {
    const int w = t >> 6, l = t & 63;
    const int c = (b - 64) * 4 + w;                    // proto 0..63
    const float4 v = *(const float4*)(protos + c * D_PROJ + l * 4);
    float ss = v.x*v.x + v.y*v.y + v.z*v.z + v.w*v.w;
#pragma unroll
    for (int m = 1; m < 64; m <<= 1) ss += __shfl_xor(ss, m);
    if (l == 0) pnorm2[c] = ss;
    ushort4 o = { f2bf(v.x), f2bf(v.y), f2bf(v.z), f2bf(v.w) };
    *(ushort4*)(protoB + c * D_PROJ + l * 4) = o;
  } else {
    const int b2  = b - 80;
    const int col = b2 * 16 + (t & 15);
    const int ks  = t >> 4;
    float s = 0.0f;
    const int kb = ks * 64;
#pragma unroll 4
    for (int k = 0; k < 64; ++k)
      s = fmaf(mean[kb + k], proj[(kb + k) * D_PROJ + col], s);
    part[ks][t & 15] = s;
    __syncthreads();
    if (t < 16) {
      float acc = 0.0f;
#pragma unroll
      for (int i = 0; i < 16; ++i) acc += part[i][t];
      mu_p[b2 * 16 + t] = acc;
    }
  }
}

// ---------------------------------------------------------------------------
// Main: 32 rows/block, 512 blocks, 512 threads (8 waves).
// GEMM1: wave w owns 32 rows x 32 cols. Step s (0..31): kt=s>>1, kk=s&1.
//   B: direct L2->VGPR, 3-step-deep prefetch (bf[4][2]).
//   A: LDS, XOR-swizzled (chunk c of row r at phys c^(r&7)); 4-tile group,
//      2 lgkm-only barriers per group, zero vmcnt drains in the k-loop.
// ---------------------------------------------------------------------------
__global__ __launch_bounds__(512, 4) void protonet_main(
    const float* __restrict__ X,               // [16384][1024]
    const unsigned short* __restrict__ projT,  // [256][1024] bf16
    const unsigned short* __restrict__ protoB, // [64][256]   bf16
    const float* __restrict__ pnorm2,          // [64]
    const float* __restrict__ mu_p,            // [256]
    float* __restrict__ out)                   // [16384][64]
{
  __shared__ unsigned short lds_A[4 * ATS];       // 16 KB: 4 k-tiles, swizzled
  __shared__ unsigned short lds_Z[BM * Z_STRIDE]; // 16.9 KB
  __shared__ float lds_part[8][BM];
  __shared__ float lds_inv[BM];
  __shared__ float lds_z2[BM];

  const int t  = threadIdx.x;
  const int w  = t >> 6;
  const int l  = t & 63;
  const int q  = l >> 4;
  const int lc = l & 15;
  const int row0 = blockIdx.x * BM;

  // A staging: thread owns row ar, kshorts aj*4..aj*4+3 (half of chunk aj>>1)
  const int ar = t >> 4;
  const int aj = t & 15;
  const float* xbase = X + (row0 + ar) * D_IN + (aj << 2);
  // swizzled write addr: row*64 + (chunk ^ (row&7))*8 + (aj&1)*4 shorts
  unsigned short* awr = lds_A + (ar << 6) + ((((aj >> 1) ^ (ar & 7)) << 3) | ((aj & 1) << 2));

  // B fragment base: col = w*32 + lc (j=0) / +16 (j=1), k-offset q*8
  const unsigned short* bp0 = projT + ((w << 5) + lc) * D_IN + (q << 3);

  float4  xf[4];       // in-flight X chunk
  ushort4 abf[4];      // converted A slices for current group
  v8s     bf[4][2];    // B prefetch ring, 3 steps deep
  v4f     acc1[4];     // [rg*2+j]: rows rg*16+, cols w*32+j*16+

#pragma unroll
  for (int j = 0; j < 4; ++j) acc1[j] = (v4f)(0.0f);

  // B pair for step S -> bf[S&3]; all offsets compile-time after unroll
#define LOADB(S) do {                                                          \
    bf[(S) & 3][0] = *(const v8s*)(bp0 + (((S) >> 1) << 6) + (((S) & 1) << 5));\
    bf[(S) & 3][1] = *(const v8s*)(bp0 + (D_IN << 4) +                         \
                                   (((S) >> 1) << 6) + (((S) & 1) << 5));      \
  } while (0)

  // A read: row lc (a0) / 16+lc (a1), chunk (4*kk+q)^(lc&7); rows 16 apart
  // share (row&7) so a1 = a0 + 1024 shorts. 2-way banks (lc vs lc+8) = free.
#define STEP(S) do {                                                           \
    if ((S) < 29) LOADB((S) + 3);                                              \
    const unsigned short* At_ = lds_A + ((((S) >> 1) & 3) << 11) + (lc << 6) + \
        ((((((S) & 1) << 2) + q) ^ (lc & 7)) << 3);                            \
    v8s a0_ = *(const v8s*)(At_);                                              \
    v8s a1_ = *(const v8s*)(At_ + 1024);                                       \
    acc1[0] = __builtin_amdgcn_mfma_f32_16x16x32_bf16(a0_, bf[(S)&3][0], acc1[0], 0, 0, 0); \
    acc1[1] = __builtin_amdgcn_mfma_f32_16x16x32_bf16(a0_, bf[(S)&3][1], acc1[1], 0, 0, 0); \
    acc1[2] = __builtin_amdgcn_mfma_f32_16x16x32_bf16(a1_, bf[(S)&3][0], acc1[2], 0, 0, 0); \
    acc1[3] = __builtin_amdgcn_mfma_f32_16x16x32_bf16(a1_, bf[(S)&3][1], acc1[3], 0, 0, 0); \
  } while (0)

  // ---- prologue: X chunk0, B steps 0-2, convert, X chunk1, write group 0 ----
#pragma unroll
  for (int i = 0; i < 4; ++i) xf[i] = *(const float4*)(xbase + (i << 6));
  LOADB(0); LOADB(1); LOADB(2);
#pragma unroll
  for (int i = 0; i < 4; ++i) {
    const float4 v = xf[i];
    ushort4 o = { f2bf(v.x), f2bf(v.y), f2bf(v.z), f2bf(v.w) };
    abf[i] = o;
  }
#pragma unroll
  for (int i = 0; i < 4; ++i) xf[i] = *(const float4*)(xbase + ((4 + i) << 6));
#pragma unroll
  for (int i = 0; i < 4; ++i) *(ushort4*)(awr + i * ATS) = abf[i];
  GBAR();

  // ---- k-loop: 4 groups x (8 steps + A re-stage) ----
#pragma unroll
  for (int g = 0; g < 4; ++g) {
#pragma unroll
    for (int s8 = 0; s8 < 8; ++s8) STEP(g * 8 + s8);
    if (g < 3) {
      // convert chunk g+1 (loaded a full group ago; waits only its own vmcnt)
#pragma unroll
      for (int i = 0; i < 4; ++i) {
        const float4 v = xf[i];
        ushort4 o = { f2bf(v.x), f2bf(v.y), f2bf(v.z), f2bf(v.w) };
        abf[i] = o;
      }
      if (g < 2) {
#pragma unroll
        for (int i = 0; i < 4; ++i)
          xf[i] = *(const float4*)(xbase + (((g + 2) * 4 + i) << 6));
      }
      GBAR();                                 // all reads of group g done
#pragma unroll
      for (int i = 0; i < 4; ++i) *(ushort4*)(awr + i * ATS) = abf[i];
      GBAR();                                 // group g+1 A visible
    }
  }

  // ---- GEMM2 proto loads issued NOW: latency hides under the Z phase ----
  const int rg2 = w >> 2;
  const int cg2 = w & 3;
  v8s pb[8];
  {
    const unsigned short* prow = protoB + ((cg2 << 4) + lc) * D_PROJ + (q << 3);
#pragma unroll
    for (int kk = 0; kk < 8; ++kk)
      pb[kk] = *(const v8s*)(prow + (kk << 5));
  }

  // ---- Zc = Zraw - mu_p -> lds_Z bf16 + fp32 row norms ----
  const float mu0 = mu_p[(w << 5) + lc];
  const float mu1 = mu_p[(w << 5) + 16 + lc];
#pragma unroll
  for (int rg = 0; rg < 2; ++rg) {
#pragma unroll
    for (int r = 0; r < 4; ++r) {
      const int row = (rg << 4) + (q << 2) + r;
      const float v0 = acc1[rg * 2 + 0][r] - mu0;
      const float v1 = acc1[rg * 2 + 1][r] - mu1;
      lds_Z[row * Z_STRIDE + (w << 5) + lc]      = f2bf(v0);
      lds_Z[row * Z_STRIDE + (w << 5) + 16 + lc] = f2bf(v1);
      float s2 = v0 * v0 + v1 * v1;
      s2 += __shfl_xor(s2, 1);
      s2 += __shfl_xor(s2, 2);
      s2 += __shfl_xor(s2, 4);
      s2 += __shfl_xor(s2, 8);
      if (lc == 0) lds_part[w][row] = s2;
    }
  }
  __syncthreads();
  if (t < BM) {
    float n2 = 0.0f;
#pragma unroll
    for (int i = 0; i < 8; ++i) n2 += lds_part[i][t];
    const float nrm = sqrtf(n2);
    const float inv = 1.0f / fmaxf(nrm, 1e-12f);   // torch/jax normalize eps
    lds_inv[t] = inv;
    lds_z2[t]  = n2 * inv * inv;                   // == 1 unless degenerate
  }
  __syncthreads();

  // ---- GEMM2: dot(Zc, proto_c); wave (rg2, cg2): 16 rows x 16 protos ----
  v4f acc2 = (v4f)(0.0f);
#pragma unroll
  for (int kk = 0; kk < 8; ++kk) {
    v8s za = *(const v8s*)(lds_Z + ((rg2 << 4) + lc) * Z_STRIDE + (kk << 5) + (q << 3));
    acc2 = __builtin_amdgcn_mfma_f32_16x16x32_bf16(za, pb[kk], acc2, 0, 0, 0);
  }

  // ---- epilogue: d^2 = ||Z||^2 + ||p||^2 - 2*dot*inv ; score = -sqrt(d^2) ----
  const int c  = (cg2 << 4) + lc;
  const float pn = pnorm2[c];
#pragma unroll
  for (int r = 0; r < 4; ++r) {
    const int row = (rg2 << 4) + (q << 2) + r;
    const float inv = lds_inv[row];
    const float d2  = lds_z2[row] + pn - 2.0f * acc2[r] * inv;
    out[(row0 + row) * N_C + c] = -sqrtf(fmaxf(d2, 0.0f));
  }
}

extern "C" void kernel_launch(void* const* d_in, const int* in_sizes, int n_in,
                              void* d_out, int out_size, void* d_ws, size_t ws_size,
                              hipStream_t stream) {
  const float* X      = (const float*)d_in[0];
  const float* protos = (const float*)d_in[1];
  const float* mean   = (const float*)d_in[2];
  const float* proj   = (const float*)d_in[3];
  float* out = (float*)d_out;

  unsigned short* projT  = (unsigned short*)d_ws;          // 256*1024 bf16 = 512 KB
  unsigned short* protoB = projT + D_PROJ * D_IN;          // 64*256  bf16 = 32 KB
  float*          pn2    = (float*)(protoB + N_C * D_PROJ);// 64 fp32
  float*          mup    = pn2 + N_C;                      // 256 fp32

  prep_kernel<<<96, 256, 0, stream>>>(proj, protos, mean, projT, protoB, pn2, mup);
  protonet_main<<<N_ROWS / BM, 512, 0, stream>>>(X, projT, protoB, pn2, mup, out);
}

// Round 6
// 123.232 us; speedup vs baseline: 1.0792x; 1.0792x over previous
//
#include <hip/hip_runtime.h>

// ============================================================================
// R6: B via global_load_lds DMA (R2-verified pattern) + DOUBLE-buffered tiles
// with counted vmcnt(6) barriers (never drains staging), + R5's 32x32 wave map
// (B wave-private in LDS, zero dup) + per-tile double-buffered A (XOR swizzle).
// Diagnosis R5: direct L2->VGPR B loads are line-miss-throughput bound
// (~20K scattered 64B lines/CU through TCP at ~0.16 lines/cy = 50 us);
// VGPR=64 showed prefetch state never fit. DMA path batches whole tiles.
// ============================================================================

#define D_IN   1024
#define D_PROJ 256
#define N_C    64
#define N_ROWS 16384
#define BM     32
#define BK     64
#define BSZ (D_PROJ * BK)   // 16384 shorts = 32 KB per B buffer
#define ATS 2048            // shorts per A tile (32 rows x 64, swizzled)
#define Z_STRIDE 264        // D_PROJ + 8 pad

typedef float v4f __attribute__((ext_vector_type(4)));
typedef short v8s __attribute__((ext_vector_type(8)));

__device__ inline unsigned short f2bf(float f) {
  unsigned int u = __float_as_uint(f);
  u = u + 0x7fffu + ((u >> 16) & 1u);   // round-to-nearest-even
  return (unsigned short)(u >> 16);
}

__device__ inline void async16(const void* g, void* s) {
  __builtin_amdgcn_global_load_lds(
      (const __attribute__((address_space(1))) unsigned int*)g,
      (__attribute__((address_space(3))) unsigned int*)s, 16, 0, 0);
}

// counted barrier: retire all but K newest VMEM ops + all lgkm, then s_barrier
#define KBAR(K) do {                                                   \
  asm volatile("s_waitcnt vmcnt(" #K ") lgkmcnt(0)" ::: "memory");     \
  __builtin_amdgcn_s_barrier();                                        \
  __builtin_amdgcn_sched_barrier(0);                                   \
} while (0)

// ---------------------------------------------------------------------------
// Prep (unchanged): projT bf16 [256][1024], protoB bf16 [64][256], pnorm2[64],
// mu_p[256] = mean @ proj
// ---------------------------------------------------------------------------
__global__ __launch_bounds__(256) void prep_kernel(
    const float* __restrict__ proj,      // [1024][256]
    const float* __restrict__ protos,    // [64][256]
    const float* __restrict__ mean,      // [1024]
    unsigned short* __restrict__ projT,  // [256][1024]
    unsigned short* __restrict__ protoB, // [64][256]
    float* __restrict__ pnorm2,          // [64]
    float* __restrict__ mu_p)            // [256]
{
  __shared__ float tile[64][65];
  __shared__ float part[16][17];
  const int b = blockIdx.x;
  const int t = threadIdx.x;
  if (b < 64) {
    const int k0 = (b & 15) * 64, n0 = (b >> 4) * 64;
    const int r = t >> 4, c4 = (t & 15) * 4;
    for (int rr = r; rr < 64; rr += 16) {
      const float4 v = *(const float4*)(proj + (k0 + rr) * D_PROJ + n0 + c4);
      tile[rr][c4 + 0] = v.x; tile[rr][c4 + 1] = v.y;
      tile[rr][c4 + 2] = v.z; tile[rr][c4 + 3] = v.w;
    }
    __syncthreads();
    const int n = t >> 2, kc = (t & 3) * 16;
    unsigned short o[16];
#pragma unroll
    for (int i = 0; i < 16; ++i) o[i] = f2bf(tile[kc + i][n]);
    unsigned short* dst = projT + (n0 + n) * D_IN + k0 + kc;
#pragma unroll
    for (int i = 0; i < 4; ++i) {
      ushort4 s4 = { o[4*i+0], o[4*i+1], o[4*i+2], o[4*i+3] };
      *(ushort4*)(dst + 4*i) = s4;
    }
  } else if (b < 80) {
    const int w = t >> 6, l = t & 63;
    const int c = (b - 64) * 4 + w;                    // proto 0..63
    const float4 v = *(const float4*)(protos + c * D_PROJ + l * 4);
    float ss = v.x*v.x + v.y*v.y + v.z*v.z + v.w*v.w;
#pragma unroll
    for (int m = 1; m < 64; m <<= 1) ss += __shfl_xor(ss, m);
    if (l == 0) pnorm2[c] = ss;
    ushort4 o = { f2bf(v.x), f2bf(v.y), f2bf(v.z), f2bf(v.w) };
    *(ushort4*)(protoB + c * D_PROJ + l * 4) = o;
  } else {
    const int b2  = b - 80;
    const int col = b2 * 16 + (t & 15);
    const int ks  = t >> 4;
    float s = 0.0f;
    const int kb = ks * 64;
#pragma unroll 4
    for (int k = 0; k < 64; ++k)
      s = fmaf(mean[kb + k], proj[(kb + k) * D_PROJ + col], s);
    part[ks][t & 15] = s;
    __syncthreads();
    if (t < 16) {
      float acc = 0.0f;
#pragma unroll
      for (int i = 0; i < 16; ++i) acc += part[i][t];
      mu_p[b2 * 16 + t] = acc;
    }
  }
}

// ---------------------------------------------------------------------------
// Main: 32 rows/block, 512 blocks, 512 threads (8 waves).
// Per tile T: [stage B(T+1) via 4 DMA][issue X(T+2), 1 float4]
//             [KBAR(6): retire B(T) only][compute T][convert+write A(T+1)]
// Wave w computes rows 0..31 x cols w*32..w*32+31 from its OWN staged B rows.
// A(T+1) write is post-compute(T): no wave can be reading Abuf[(T+1)&1]
// (they read Abuf[T&1] until the next barrier). One barrier per tile.
// ---------------------------------------------------------------------------
__global__ __launch_bounds__(512, 4) void protonet_main(
    const float* __restrict__ X,               // [16384][1024]
    const unsigned short* __restrict__ projT,  // [256][1024] bf16
    const unsigned short* __restrict__ protoB, // [64][256]   bf16
    const float* __restrict__ pnorm2,          // [64]
    const float* __restrict__ mu_p,            // [256]
    float* __restrict__ out)                   // [16384][64]
{
  __shared__ unsigned short lds_A[2 * ATS];   // 8 KB, double-buffered, swizzled
  __shared__ unsigned short lds_B[2 * BSZ];   // 64 KB, double-buffered (Z alias)
  __shared__ float lds_part[8][BM];
  __shared__ float lds_inv[BM];
  __shared__ float lds_z2[BM];

  const int t  = threadIdx.x;
  const int w  = t >> 6;
  const int l  = t & 63;
  const int q  = l >> 4;
  const int lc = l & 15;
  const int row0 = blockIdx.x * BM;

  // B DMA src (R2-verified): instr s covers rows 32w+8s..+7; lane l -> row
  // +(l>>3), phys chunk l&7 holds logical (l&7)^(row&7) via pre-swizzled src.
  const int bsrc0 = ((w << 5) + (l >> 3)) * D_IN + (((l & 7) ^ ((l >> 3) & 7)) << 3);
  const int bdst0 = (w << 5) * BK;   // wave-uniform LDS base (+ s*8*BK per instr)

  // A staging: thread owns row ar, 4 shorts at aj*4 per tile (XOR-swizzled)
  const int ar = t >> 4;
  const int aj = t & 15;
  const float* xbase = X + (row0 + ar) * D_IN + (aj << 2);
  unsigned short* awr = lds_A + (ar << 6) + ((((aj >> 1) ^ (ar & 7)) << 3) | ((aj & 1) << 2));

  float4 xf[2];        // X in flight: slot = tile&1
  v4f acc1[4];         // [rg*2+j]: rows rg*16.. x cols w*32+j*16..
#pragma unroll
  for (int j = 0; j < 4; ++j) acc1[j] = (v4f)(0.0f);

#define STAGEB(T) do {                                                    \
    _Pragma("unroll")                                                     \
    for (int s_ = 0; s_ < 4; ++s_)                                        \
      async16(projT + bsrc0 + s_ * (8 * D_IN) + (T) * BK,                 \
              lds_B + (((T) & 1) * BSZ) + bdst0 + ((s_ << 3) * BK));      \
  } while (0)

#define CVTWR(T) do {                                                     \
    const float4 v_ = xf[(T) & 1];                                        \
    ushort4 o_ = { f2bf(v_.x), f2bf(v_.y), f2bf(v_.z), f2bf(v_.w) };      \
    *(ushort4*)(awr + (((T) & 1) << 11)) = o_;                            \
  } while (0)

#define COMPUTE(T) do {                                                   \
    const unsigned short* Ab_ = lds_A + (((T) & 1) << 11);                \
    const unsigned short* Bb_ = lds_B + (((T) & 1) * BSZ);                \
    _Pragma("unroll")                                                     \
    for (int kk_ = 0; kk_ < 2; ++kk_) {                                   \
      const int po_ = (((kk_ << 2) + q) ^ (lc & 7)) << 3;                 \
      v8s a0_ = *(const v8s*)(Ab_ + (lc << 6) + po_);                     \
      v8s a1_ = *(const v8s*)(Ab_ + 1024 + (lc << 6) + po_);              \
      v8s b0_ = *(const v8s*)(Bb_ + ((w << 5) + lc) * BK + po_);          \
      v8s b1_ = *(const v8s*)(Bb_ + ((w << 5) + 16 + lc) * BK + po_);     \
      acc1[0] = __builtin_amdgcn_mfma_f32_16x16x32_bf16(a0_, b0_, acc1[0], 0, 0, 0); \
      acc1[1] = __builtin_amdgcn_mfma_f32_16x16x32_bf16(a0_, b1_, acc1[1], 0, 0, 0); \
      acc1[2] = __builtin_amdgcn_mfma_f32_16x16x32_bf16(a1_, b0_, acc1[2], 0, 0, 0); \
      acc1[3] = __builtin_amdgcn_mfma_f32_16x16x32_bf16(a1_, b1_, acc1[3], 0, 0, 0); \
    }                                                                     \
  } while (0)

  // ---- prologue: X(0), stage B(0), X(1), A(0) -> Abuf[0] ----
  xf[0] = *(const float4*)(xbase);
  STAGEB(0);
  xf[1] = *(const float4*)(xbase + (1 << 6));
  CVTWR(0);                                  // waits xf[0] only (vmcnt counted)

  // ---- k-loop: one barrier per tile, staging never drained ----
#pragma unroll
  for (int T = 0; T < 16; ++T) {
    if (T < 15) STAGEB(T + 1);
    if (T <= 13) xf[T & 1] = *(const float4*)(xbase + ((T + 2) << 6));
    // vmcnt: newer-than-B(T) = X(T+1)[1] + B(T+1)[4] + X(T+2)[1] = 6 (T<=13);
    //        T=14: X(15)[1]+B(15)[4] = 5;  T=15: 0.
    if (T <= 13)      KBAR(6);
    else if (T == 14) KBAR(5);
    else              KBAR(0);
    COMPUTE(T);
    if (T < 15) CVTWR(T + 1);               // post-compute: Abuf[(T+1)&1] is idle
  }

  // ---- GEMM2 proto loads issued now: latency hides under the Z phase ----
  const int rg2 = w >> 2;
  const int cg2 = w & 3;
  v8s pb[8];
  {
    const unsigned short* prow = protoB + ((cg2 << 4) + lc) * D_PROJ + (q << 3);
#pragma unroll
    for (int kk = 0; kk < 8; ++kk)
      pb[kk] = *(const v8s*)(prow + (kk << 5));
  }

  // ---- Zc = Zraw - mu_p -> Z (alias of B buf0; compute(15) used buf1) ----
  unsigned short* lds_Z = lds_B;
  const float mu0 = mu_p[(w << 5) + lc];
  const float mu1 = mu_p[(w << 5) + 16 + lc];
#pragma unroll
  for (int rg = 0; rg < 2; ++rg) {
#pragma unroll
    for (int r = 0; r < 4; ++r) {
      const int row = (rg << 4) + (q << 2) + r;
      const float v0 = acc1[rg * 2 + 0][r] - mu0;
      const float v1 = acc1[rg * 2 + 1][r] - mu1;
      lds_Z[row * Z_STRIDE + (w << 5) + lc]      = f2bf(v0);
      lds_Z[row * Z_STRIDE + (w << 5) + 16 + lc] = f2bf(v1);
      float s2 = v0 * v0 + v1 * v1;
      s2 += __shfl_xor(s2, 1);
      s2 += __shfl_xor(s2, 2);
      s2 += __shfl_xor(s2, 4);
      s2 += __shfl_xor(s2, 8);
      if (lc == 0) lds_part[w][row] = s2;
    }
  }
  __syncthreads();
  if (t < BM) {
    float n2 = 0.0f;
#pragma unroll
    for (int i = 0; i < 8; ++i) n2 += lds_part[i][t];
    const float nrm = sqrtf(n2);
    const float inv = 1.0f / fmaxf(nrm, 1e-12f);   // torch/jax normalize eps
    lds_inv[t] = inv;
    lds_z2[t]  = n2 * inv * inv;                   // == 1 unless degenerate
  }
  __syncthreads();

  // ---- GEMM2: dot(Zc, proto_c); wave (rg2, cg2): 16 rows x 16 protos ----
  v4f acc2 = (v4f)(0.0f);
#pragma unroll
  for (int kk = 0; kk < 8; ++kk) {
    v8s za = *(const v8s*)(lds_Z + ((rg2 << 4) + lc) * Z_STRIDE + (kk << 5) + (q << 3));
    acc2 = __builtin_amdgcn_mfma_f32_16x16x32_bf16(za, pb[kk], acc2, 0, 0, 0);
  }

  // ---- epilogue: d^2 = ||Z||^2 + ||p||^2 - 2*dot*inv ; score = -sqrt(d^2) ----
  const int c  = (cg2 << 4) + lc;
  const float pn = pnorm2[c];
#pragma unroll
  for (int r = 0; r < 4; ++r) {
    const int row = (rg2 << 4) + (q << 2) + r;
    const float inv = lds_inv[row];
    const float d2  = lds_z2[row] + pn - 2.0f * acc2[r] * inv;
    out[(row0 + row) * N_C + c] = -sqrtf(fmaxf(d2, 0.0f));
  }
}

extern "C" void kernel_launch(void* const* d_in, const int* in_sizes, int n_in,
                              void* d_out, int out_size, void* d_ws, size_t ws_size,
                              hipStream_t stream) {
  const float* X      = (const float*)d_in[0];
  const float* protos = (const float*)d_in[1];
  const float* mean   = (const float*)d_in[2];
  const float* proj   = (const float*)d_in[3];
  float* out = (float*)d_out;

  unsigned short* projT  = (unsigned short*)d_ws;          // 256*1024 bf16 = 512 KB
  unsigned short* protoB = projT + D_PROJ * D_IN;          // 64*256  bf16 = 32 KB
  float*          pn2    = (float*)(protoB + N_C * D_PROJ);// 64 fp32
  float*          mup    = pn2 + N_C;                      // 256 fp32

  prep_kernel<<<96, 256, 0, stream>>>(proj, protos, mean, projT, protoB, pn2, mup);
  protonet_main<<<N_ROWS / BM, 512, 0, stream>>>(X, projT, protoB, pn2, mup, out);
}

// Round 7
// 118.932 us; speedup vs baseline: 1.1182x; 1.0362x over previous
//
#include <hip/hip_runtime.h>

// ============================================================================
// R7: BM 32 -> 64 (B traffic per CU halves: it scales 1/BM), 256 blocks,
// 1 block/CU, triple-buffered B DMA (2-tile-deep pipeline, KBAR(14) steady),
// double-buffered A, __launch_bounds__(512,2) (R4-R6 had (512,4) silently
// capping VGPR=64). Diagnosis R6: R2 (full drains) and R6 (zero drains) both
// land ~31-35 us -> traffic-bound, not schedule-bound; B bytes/CU is the knob.
// ============================================================================

#define D_IN   1024
#define D_PROJ 256
#define N_C    64
#define N_ROWS 16384
#define BM     64
#define BK     64
#define BSZ (D_PROJ * BK)   // 16384 shorts = 32 KB per B buffer
#define ATS 4096            // shorts per A tile (64 rows x 64 k, swizzled)
#define Z_STRIDE 264        // D_PROJ + 8 pad

typedef float v4f __attribute__((ext_vector_type(4)));
typedef short v8s __attribute__((ext_vector_type(8)));

__device__ inline unsigned short f2bf(float f) {
  unsigned int u = __float_as_uint(f);
  u = u + 0x7fffu + ((u >> 16) & 1u);   // round-to-nearest-even
  return (unsigned short)(u >> 16);
}

__device__ inline void async16(const void* g, void* s) {
  __builtin_amdgcn_global_load_lds(
      (const __attribute__((address_space(1))) unsigned int*)g,
      (__attribute__((address_space(3))) unsigned int*)s, 16, 0, 0);
}

// counted barrier: retire all but K newest VMEM ops + all lgkm, then s_barrier
#define KBAR(K) do {                                                   \
  asm volatile("s_waitcnt vmcnt(" #K ") lgkmcnt(0)" ::: "memory");     \
  __builtin_amdgcn_s_barrier();                                        \
  __builtin_amdgcn_sched_barrier(0);                                   \
} while (0)

// ---------------------------------------------------------------------------
// Prep (unchanged): projT bf16 [256][1024], protoB bf16 [64][256], pnorm2[64],
// mu_p[256] = mean @ proj
// ---------------------------------------------------------------------------
__global__ __launch_bounds__(256) void prep_kernel(
    const float* __restrict__ proj,      // [1024][256]
    const float* __restrict__ protos,    // [64][256]
    const float* __restrict__ mean,      // [1024]
    unsigned short* __restrict__ projT,  // [256][1024]
    unsigned short* __restrict__ protoB, // [64][256]
    float* __restrict__ pnorm2,          // [64]
    float* __restrict__ mu_p)            // [256]
{
  __shared__ float tile[64][65];
  __shared__ float part[16][17];
  const int b = blockIdx.x;
  const int t = threadIdx.x;
  if (b < 64) {
    const int k0 = (b & 15) * 64, n0 = (b >> 4) * 64;
    const int r = t >> 4, c4 = (t & 15) * 4;
    for (int rr = r; rr < 64; rr += 16) {
      const float4 v = *(const float4*)(proj + (k0 + rr) * D_PROJ + n0 + c4);
      tile[rr][c4 + 0] = v.x; tile[rr][c4 + 1] = v.y;
      tile[rr][c4 + 2] = v.z; tile[rr][c4 + 3] = v.w;
    }
    __syncthreads();
    const int n = t >> 2, kc = (t & 3) * 16;
    unsigned short o[16];
#pragma unroll
    for (int i = 0; i < 16; ++i) o[i] = f2bf(tile[kc + i][n]);
    unsigned short* dst = projT + (n0 + n) * D_IN + k0 + kc;
#pragma unroll
    for (int i = 0; i < 4; ++i) {
      ushort4 s4 = { o[4*i+0], o[4*i+1], o[4*i+2], o[4*i+3] };
      *(ushort4*)(dst + 4*i) = s4;
    }
  } else if (b < 80) {
    const int w = t >> 6, l = t & 63;
    const int c = (b - 64) * 4 + w;                    // proto 0..63
    const float4 v = *(const float4*)(protos + c * D_PROJ + l * 4);
    float ss = v.x*v.x + v.y*v.y + v.z*v.z + v.w*v.w;
#pragma unroll
    for (int m = 1; m < 64; m <<= 1) ss += __shfl_xor(ss, m);
    if (l == 0) pnorm2[c] = ss;
    ushort4 o = { f2bf(v.x), f2bf(v.y), f2bf(v.z), f2bf(v.w) };
    *(ushort4*)(protoB + c * D_PROJ + l * 4) = o;
  } else {
    const int b2  = b - 80;
    const int col = b2 * 16 + (t & 15);
    const int ks  = t >> 4;
    float s = 0.0f;
    const int kb = ks * 64;
#pragma unroll 4
    for (int k = 0; k < 64; ++k)
      s = fmaf(mean[kb + k], proj[(kb + k) * D_PROJ + col], s);
    part[ks][t & 15] = s;
    __syncthreads();
    if (t < 16) {
      float acc = 0.0f;
#pragma unroll
      for (int i = 0; i < 16; ++i) acc += part[i][t];
      mu_p[b2 * 16 + t] = acc;
    }
  }
}

// ---------------------------------------------------------------------------
// Main: 64 rows/block, 256 blocks (1/CU), 512 threads (8 waves).
// Wave w: rows 0..63 x cols w*32..w*32+31 (B wave-private in LDS).
// Iter T: STAGEB(T+2)[4 DMA] ; XLD(T+3)[2] ; KBAR(14) [retires B(T) exactly,
// leaves X(T+1),B(T+1),X(T+2),B(T+2),X(T+3) = 14 in flight] ; COMPUTE(T)
// [2 ksteps x (4 A + 2 B ds_read_b128 + 8 MFMA)] ; CVTWR(T+1) [A ds_write].
// ---------------------------------------------------------------------------
__global__ __launch_bounds__(512, 2) void protonet_main(
    const float* __restrict__ X,               // [16384][1024]
    const unsigned short* __restrict__ projT,  // [256][1024] bf16
    const unsigned short* __restrict__ protoB, // [64][256]   bf16
    const float* __restrict__ pnorm2,          // [64]
    const float* __restrict__ mu_p,            // [256]
    float* __restrict__ out)                   // [16384][64]
{
  __shared__ unsigned short lds_A[2 * ATS];   // 16 KB, double-buffered, swizzled
  __shared__ unsigned short lds_B[3 * BSZ];   // 96 KB, triple-buffered (Z alias)
  __shared__ float lds_part[8][BM];
  __shared__ float lds_inv[BM];
  __shared__ float lds_z2[BM];

  const int t  = threadIdx.x;
  const int w  = t >> 6;
  const int l  = t & 63;
  const int q  = l >> 4;
  const int lc = l & 15;
  const int row0 = blockIdx.x * BM;

  // B DMA src (R2/R6-verified): instr s covers rows 32w+8s..+7; lane l -> row
  // +(l>>3); phys chunk l&7 holds logical (l&7)^(row&7) via pre-swizzled src.
  const int bsrc0 = ((w << 5) + (l >> 3)) * D_IN + (((l & 7) ^ ((l >> 3) & 7)) << 3);
  const int bdst0 = (w << 5) * BK;   // wave-uniform LDS base (+ s*8*BK per instr)

  // A staging: thread owns row ar (0..63), k-chunk aj (0..7) = 8 floats/tile
  const int ar = t >> 3;
  const int aj = t & 7;
  const float* xbase = X + (row0 + ar) * D_IN + (aj << 3);
  unsigned short* awr = lds_A + (ar << 6) + ((aj ^ (ar & 7)) << 3);

  float4 xf[3][2];     // X in flight, slot T%3 (3 tiles deep)
  v4f acc1[8];         // [a*2+j]: rows a*16.. x cols w*32+j*16..
#pragma unroll
  for (int j = 0; j < 8; ++j) acc1[j] = (v4f)(0.0f);

#define STAGEB(T) do {                                                    \
    _Pragma("unroll")                                                     \
    for (int s_ = 0; s_ < 4; ++s_)                                        \
      async16(projT + bsrc0 + s_ * (8 * D_IN) + (T) * BK,                 \
              lds_B + (((T) % 3) * BSZ) + bdst0 + ((s_ << 3) * BK));      \
  } while (0)

#define XLD(T) do {                                                       \
    xf[(T) % 3][0] = *(const float4*)(xbase + ((T) << 6));                \
    xf[(T) % 3][1] = *(const float4*)(xbase + ((T) << 6) + 4);            \
  } while (0)

#define CVTWR(T) do {                                                     \
    const float4 f0_ = xf[(T) % 3][0], f1_ = xf[(T) % 3][1];              \
    v8s o_;                                                               \
    o_[0] = f2bf(f0_.x); o_[1] = f2bf(f0_.y);                             \
    o_[2] = f2bf(f0_.z); o_[3] = f2bf(f0_.w);                             \
    o_[4] = f2bf(f1_.x); o_[5] = f2bf(f1_.y);                             \
    o_[6] = f2bf(f1_.z); o_[7] = f2bf(f1_.w);                             \
    *(v8s*)(awr + (((T) & 1) << 12)) = o_;                                \
  } while (0)

#define COMPUTE(T) do {                                                   \
    const unsigned short* Ab_ = lds_A + (((T) & 1) << 12);                \
    const unsigned short* Bb_ = lds_B + (((T) % 3) * BSZ);                \
    _Pragma("unroll")                                                     \
    for (int kk_ = 0; kk_ < 2; ++kk_) {                                   \
      const int po_ = (((kk_ << 2) + q) ^ (lc & 7)) << 3;                 \
      v8s a0_ = *(const v8s*)(Ab_ + (lc << 6) + po_);                     \
      v8s a1_ = *(const v8s*)(Ab_ + 1024 + (lc << 6) + po_);              \
      v8s a2_ = *(const v8s*)(Ab_ + 2048 + (lc << 6) + po_);              \
      v8s a3_ = *(const v8s*)(Ab_ + 3072 + (lc << 6) + po_);              \
      v8s b0_ = *(const v8s*)(Bb_ + ((w << 5) + lc) * BK + po_);          \
      v8s b1_ = *(const v8s*)(Bb_ + ((w << 5) + 16 + lc) * BK + po_);     \
      acc1[0] = __builtin_amdgcn_mfma_f32_16x16x32_bf16(a0_, b0_, acc1[0], 0, 0, 0); \
      acc1[1] = __builtin_amdgcn_mfma_f32_16x16x32_bf16(a0_, b1_, acc1[1], 0, 0, 0); \
      acc1[2] = __builtin_amdgcn_mfma_f32_16x16x32_bf16(a1_, b0_, acc1[2], 0, 0, 0); \
      acc1[3] = __builtin_amdgcn_mfma_f32_16x16x32_bf16(a1_, b1_, acc1[3], 0, 0, 0); \
      acc1[4] = __builtin_amdgcn_mfma_f32_16x16x32_bf16(a2_, b0_, acc1[4], 0, 0, 0); \
      acc1[5] = __builtin_amdgcn_mfma_f32_16x16x32_bf16(a2_, b1_, acc1[5], 0, 0, 0); \
      acc1[6] = __builtin_amdgcn_mfma_f32_16x16x32_bf16(a3_, b0_, acc1[6], 0, 0, 0); \
      acc1[7] = __builtin_amdgcn_mfma_f32_16x16x32_bf16(a3_, b1_, acc1[7], 0, 0, 0); \
    }                                                                     \
  } while (0)

  // ---- prologue: X(0),B(0),X(1),B(1),X(2); convert+write A(0) ----
  XLD(0);
  STAGEB(0);
  XLD(1);
  STAGEB(1);
  XLD(2);
  CVTWR(0);                       // waits X(0) only (12 newer ops stay in flight)
  __builtin_amdgcn_sched_barrier(0);

  // ---- k-loop: one barrier per tile; 2-tile-deep B pipeline ----
#pragma unroll
  for (int T = 0; T < 16; ++T) {
    if (T <= 13) STAGEB(T + 2);
    if (T <= 12) XLD(T + 3);
    // in-flight newer than B(T): X(T+1)2 B(T+1)4 X(T+2)2 B(T+2)4 X(T+3)2
    if (T <= 12)      KBAR(14);
    else if (T == 13) KBAR(12);
    else if (T == 14) KBAR(6);
    else              KBAR(0);
    COMPUTE(T);
    if (T <= 14) CVTWR(T + 1);    // A buf (T+1)&1: idle since KBAR(T)
  }

  // ---- GEMM2 proto loads issued now: latency hides under the Z phase ----
  const int rw = w >> 2;          // 0..1: rows rw*32..+31
  const int cw = w & 3;           // 0..3: protos cw*16..+15
  v8s pb[8];
  {
    const unsigned short* prow = protoB + ((cw << 4) + lc) * D_PROJ + (q << 3);
#pragma unroll
    for (int kk = 0; kk < 8; ++kk)
      pb[kk] = *(const v8s*)(prow + (kk << 5));
  }

  __syncthreads();                // compute(15) read B buf0 = Z alias region

  // ---- Zc = Zraw - mu_p -> Z (aliases lds_B) + fp32 row norms ----
  unsigned short* lds_Z = lds_B;
  const float mu0 = mu_p[(w << 5) + lc];
  const float mu1 = mu_p[(w << 5) + 16 + lc];
#pragma unroll
  for (int a = 0; a < 4; ++a) {
#pragma unroll
    for (int r = 0; r < 4; ++r) {
      const int row = (a << 4) + (q << 2) + r;
      const float v0 = acc1[a * 2 + 0][r] - mu0;
      const float v1 = acc1[a * 2 + 1][r] - mu1;
      lds_Z[row * Z_STRIDE + (w << 5) + lc]      = f2bf(v0);
      lds_Z[row * Z_STRIDE + (w << 5) + 16 + lc] = f2bf(v1);
      float s2 = v0 * v0 + v1 * v1;
      s2 += __shfl_xor(s2, 1);
      s2 += __shfl_xor(s2, 2);
      s2 += __shfl_xor(s2, 4);
      s2 += __shfl_xor(s2, 8);
      if (lc == 0) lds_part[w][row] = s2;
    }
  }
  __syncthreads();
  if (t < BM) {
    float n2 = 0.0f;
#pragma unroll
    for (int i = 0; i < 8; ++i) n2 += lds_part[i][t];
    const float nrm = sqrtf(n2);
    const float inv = 1.0f / fmaxf(nrm, 1e-12f);   // torch/jax normalize eps
    lds_inv[t] = inv;
    lds_z2[t]  = n2 * inv * inv;                   // == 1 unless degenerate
  }
  __syncthreads();

  // ---- GEMM2: dot(Zc, proto_c); wave (rw, cw): 32 rows x 16 protos ----
  v4f acc2[2] = { (v4f)(0.0f), (v4f)(0.0f) };
#pragma unroll
  for (int kk = 0; kk < 8; ++kk) {
#pragma unroll
    for (int sr = 0; sr < 2; ++sr) {
      v8s za = *(const v8s*)(lds_Z + ((rw << 5) + (sr << 4) + lc) * Z_STRIDE +
                             (kk << 5) + (q << 3));
      acc2[sr] = __builtin_amdgcn_mfma_f32_16x16x32_bf16(za, pb[kk], acc2[sr], 0, 0, 0);
    }
  }

  // ---- epilogue: d^2 = ||Z||^2 + ||p||^2 - 2*dot*inv ; score = -sqrt(d^2) ----
  const int c  = (cw << 4) + lc;
  const float pn = pnorm2[c];
#pragma unroll
  for (int sr = 0; sr < 2; ++sr) {
#pragma unroll
    for (int r = 0; r < 4; ++r) {
      const int row = (rw << 5) + (sr << 4) + (q << 2) + r;
      const float inv = lds_inv[row];
      const float d2  = lds_z2[row] + pn - 2.0f * acc2[sr][r] * inv;
      out[(row0 + row) * N_C + c] = -sqrtf(fmaxf(d2, 0.0f));
    }
  }
}

extern "C" void kernel_launch(void* const* d_in, const int* in_sizes, int n_in,
                              void* d_out, int out_size, void* d_ws, size_t ws_size,
                              hipStream_t stream) {
  const float* X      = (const float*)d_in[0];
  const float* protos = (const float*)d_in[1];
  const float* mean   = (const float*)d_in[2];
  const float* proj   = (const float*)d_in[3];
  float* out = (float*)d_out;

  unsigned short* projT  = (unsigned short*)d_ws;          // 256*1024 bf16 = 512 KB
  unsigned short* protoB = projT + D_PROJ * D_IN;          // 64*256  bf16 = 32 KB
  float*          pn2    = (float*)(protoB + N_C * D_PROJ);// 64 fp32
  float*          mup    = pn2 + N_C;                      // 256 fp32

  prep_kernel<<<96, 256, 0, stream>>>(proj, protos, mean, projT, protoB, pn2, mup);
  protonet_main<<<N_ROWS / BM, 512, 0, stream>>>(X, projT, protoB, pn2, mup, out);
}